// Round 4
// baseline (245.935 us; speedup 1.0000x reference)
//
#include <hip/hip_runtime.h>
#include <stdint.h>

#define B_   128
#define N_   512
#define FIN  128
#define FOUT 64

using bf16x8 = __attribute__((ext_vector_type(8))) short;
using f32x4  = __attribute__((ext_vector_type(4))) float;

__device__ inline unsigned short f2bf(float x) {
    union { float f; uint32_t u; } c; c.f = x;
    uint32_t u = c.u;
    return (unsigned short)((u + 0x7FFFu + ((u >> 16) & 1u)) >> 16);  // RNE
}

// ---------------- kernel 1: h = X @ W via bf16 MFMA ----------------
// grid 512 = (b<<2)|quarter, 256 threads. W staged in LDS (16 KB); A-fragments
// loaded DIRECTLY from global (each is used once by one wave -- LDS staging of
// X was pure overhead). Writes htT[b][f][j] bf16 + s,t fp32.
__global__ __launch_bounds__(256) void k_h(const float* __restrict__ X,
                                           const float* __restrict__ W,
                                           const float* __restrict__ a,
                                           uint16_t* __restrict__ htT,
                                           float* __restrict__ s,
                                           float* __restrict__ t) {
    __shared__ bf16x8 wl[16 * 64];   // W fragments: 4 ks x 4 nt, 16 KB

    const int b  = blockIdx.x >> 2;
    const int j0 = (blockIdx.x & 3) * 128;
    const int tid = threadIdx.x;
    const int w = tid >> 6, lane = tid & 63;
    const int q = lane >> 4, m = lane & 15;

    // ---- stage W fragments (ks = w): B[k][n], k=q*8+u, n=m ----
#pragma unroll
    for (int nt = 0; nt < 4; ++nt) {
        bf16x8 fr;
#pragma unroll
        for (int u = 0; u < 8; ++u)
            fr[u] = (short)f2bf(W[(w * 32 + q * 8 + u) * FOUT + nt * 16 + m]);
        wl[(w * 4 + nt) * 64 + lane] = fr;
    }
    __syncthreads();

    float asv[4], adv[4];
#pragma unroll
    for (int nt = 0; nt < 4; ++nt) {
        asv[nt] = a[nt * 16 + m];
        adv[nt] = a[FOUT + nt * 16 + m];
    }

    const float* xb = X + ((size_t)(b * N_) + j0) * FIN;

    for (int rl = 0; rl < 2; ++rl) {
        const int rt = w + rl * 4;
        const float* xrow = xb + (size_t)(rt * 16 + m) * FIN + q * 8;
        f32x4 acc[4] = {{0.f,0.f,0.f,0.f},{0.f,0.f,0.f,0.f},
                        {0.f,0.f,0.f,0.f},{0.f,0.f,0.f,0.f}};
#pragma unroll
        for (int ks = 0; ks < 4; ++ks) {
            float4 v0 = *(const float4*)(xrow + ks * 32);
            float4 v1 = *(const float4*)(xrow + ks * 32 + 4);
            bf16x8 af;
            af[0] = (short)f2bf(v0.x); af[1] = (short)f2bf(v0.y);
            af[2] = (short)f2bf(v0.z); af[3] = (short)f2bf(v0.w);
            af[4] = (short)f2bf(v1.x); af[5] = (short)f2bf(v1.y);
            af[6] = (short)f2bf(v1.z); af[7] = (short)f2bf(v1.w);
#pragma unroll
            for (int nt = 0; nt < 4; ++nt)
                acc[nt] = __builtin_amdgcn_mfma_f32_16x16x32_bf16(
                    af, wl[(ks * 4 + nt) * 64 + lane], acc[nt], 0, 0, 0);
        }

        // ---- s,t: per C-row dot with a_src/a_dst, reduce over m lanes ----
        float ps[4], pt[4];
#pragma unroll
        for (int r = 0; r < 4; ++r) {
            float vs = 0.f, vt = 0.f;
#pragma unroll
            for (int nt = 0; nt < 4; ++nt) {
                vs += acc[nt][r] * asv[nt];
                vt += acc[nt][r] * adv[nt];
            }
            vs += __shfl_xor(vs, 1, 64); vs += __shfl_xor(vs, 2, 64);
            vs += __shfl_xor(vs, 4, 64); vs += __shfl_xor(vs, 8, 64);
            vt += __shfl_xor(vt, 1, 64); vt += __shfl_xor(vt, 2, 64);
            vt += __shfl_xor(vt, 4, 64); vt += __shfl_xor(vt, 8, 64);
            ps[r] = vs; pt[r] = vt;
        }
        if (m < 4) {
            float vs = (m == 0) ? ps[0] : (m == 1) ? ps[1] : (m == 2) ? ps[2] : ps[3];
            float vt = (m == 0) ? pt[0] : (m == 1) ? pt[1] : (m == 2) ? pt[2] : pt[3];
            int row = j0 + rt * 16 + q * 4 + m;
            s[b * N_ + row] = vs;
            t[b * N_ + row] = vt;
        }

        // ---- store htT[b][f][j] bf16: C row=q*4+reg -> j, col=m -> f ----
#pragma unroll
        for (int nt = 0; nt < 4; ++nt) {
            uint32_t d0 = (uint32_t)f2bf(acc[nt][0]) | ((uint32_t)f2bf(acc[nt][1]) << 16);
            uint32_t d1 = (uint32_t)f2bf(acc[nt][2]) | ((uint32_t)f2bf(acc[nt][3]) << 16);
            uint2 dd; dd.x = d0; dd.y = d1;
            *(uint2*)(htT + (size_t)(b * FOUT + nt * 16 + m) * N_ + j0 + rt * 16 + q * 4) = dd;
        }
    }
}

// ---------------- kernel 2: attention + aggregation (bf16 MFMA) ----------------
// grid 1024 = (b<<3)|eighth (64 rows/block), 256 threads, one row-tile per wave.
// hstage chunked: 32 KB holds ks 0..7, restaged mid-kernel for ks 8..15 ->
// 34 KB LDS -> 4 blocks/CU -> 4 waves/SIMD (2x round-3 latency hiding).
// htT re-reads are L2/LLC-resident (8 MB total), so HBM traffic ~unchanged.
__global__ __launch_bounds__(256, 4) void k_attn(const int*    __restrict__ adj,
                                                 const uint16_t* __restrict__ htT,
                                                 const float*  __restrict__ s,
                                                 const float*  __restrict__ t,
                                                 float*        __restrict__ out) {
    __shared__ bf16x8 hstage[32 * 64];   // 32 KB, chunk of 8 ks
    __shared__ float  tsh[N_];           // 2 KB

    const int b  = blockIdx.x >> 3;
    const int i0 = (blockIdx.x & 7) * 64;
    const int tid = threadIdx.x;
    const int w = tid >> 6, lane = tid & 63;
    const int q = lane >> 4, m = lane & 15;

    const uint16_t* hb = htT + (size_t)b * FOUT * N_;

    // ---- stage chunk 0 (ks 0..7) + t ----
#pragma unroll
    for (int i = 0; i < 8; ++i) {
        int pi = i * 4 + w, ks = pi >> 2, nt = pi & 3;
        hstage[pi * 64 + lane] =
            *(const bf16x8*)(hb + (size_t)(nt * 16 + m) * N_ + ks * 32 + q * 8);
    }
    *(float2*)&tsh[tid * 2] = *(const float2*)(t + b * N_ + tid * 2);
    __syncthreads();

    const int irow = i0 + w * 16 + m;
    const float s_i = s[b * N_ + irow];
    const int* ar = adj + ((size_t)(b * N_) + irow) * N_;

    f32x4 acc[4] = {{0.f,0.f,0.f,0.f},{0.f,0.f,0.f,0.f},
                    {0.f,0.f,0.f,0.f},{0.f,0.f,0.f,0.f}};
    float lsum = 0.f;

    // prefetch ks = 0
    int4 c0 = *(const int4*)(ar + q * 8);
    int4 c1 = *(const int4*)(ar + q * 8 + 4);

    for (int half = 0; half < 2; ++half) {
        for (int kk = 0; kk < 8; ++kk) {
            const int ks = half * 8 + kk;
            // prefetch next ks (clamped, branch-free; survives the mid barrier)
            const int jn = ((ks < 15) ? ks + 1 : ks) * 32 + q * 8;
            int4 n0 = *(const int4*)(ar + jn);
            int4 n1 = *(const int4*)(ar + jn + 4);

            const int jb = ks * 32 + q * 8;
            float tj[8];
#pragma unroll
            for (int u = 0; u < 8; ++u) tj[u] = tsh[jb + u];

            int av[8] = {c0.x, c0.y, c0.z, c0.w, c1.x, c1.y, c1.z, c1.w};
            bf16x8 af;
            float pv[8];
#pragma unroll
            for (int u = 0; u < 8; ++u) {
                float e = s_i + tj[u];
                e = fmaxf(e, 0.2f * e);               // leaky_relu(e, 0.2)
                pv[u] = (av[u] > 0) ? __expf(e) : 0.0f;
                lsum += pv[u];
                af[u] = (short)f2bf(pv[u]);
            }

            bf16x8 bf0 = hstage[(kk * 4 + 0) * 64 + lane];
            bf16x8 bf1 = hstage[(kk * 4 + 1) * 64 + lane];
            bf16x8 bf2 = hstage[(kk * 4 + 2) * 64 + lane];
            bf16x8 bf3 = hstage[(kk * 4 + 3) * 64 + lane];

            acc[0] = __builtin_amdgcn_mfma_f32_16x16x32_bf16(af, bf0, acc[0], 0, 0, 0);
            acc[1] = __builtin_amdgcn_mfma_f32_16x16x32_bf16(af, bf1, acc[1], 0, 0, 0);
            acc[2] = __builtin_amdgcn_mfma_f32_16x16x32_bf16(af, bf2, acc[2], 0, 0, 0);
            acc[3] = __builtin_amdgcn_mfma_f32_16x16x32_bf16(af, bf3, acc[3], 0, 0, 0);

            c0 = n0; c1 = n1;
        }
        if (half == 0) {
            __syncthreads();   // all chunk-0 reads done
#pragma unroll
            for (int i = 0; i < 8; ++i) {
                int pi = i * 4 + w, ks = 8 + (pi >> 2), nt = pi & 3;
                hstage[pi * 64 + lane] =
                    *(const bf16x8*)(hb + (size_t)(nt * 16 + m) * N_ + ks * 32 + q * 8);
            }
            __syncthreads();
        }
    }

    // row-sum l over q groups (lanes differ in bits 4,5)
    lsum += __shfl_xor(lsum, 16, 64);
    lsum += __shfl_xor(lsum, 32, 64);

#pragma unroll
    for (int reg = 0; reg < 4; ++reg) {
        float lr = __shfl(lsum, q * 4 + reg, 64);
        float inv = 1.0f / lr;
        int orow = i0 + w * 16 + q * 4 + reg;
        size_t ob = ((size_t)(b * N_) + orow) * FOUT + m;
#pragma unroll
        for (int nt = 0; nt < 4; ++nt) {
            float v = acc[nt][reg] * inv;
            v = fmaxf(v, 0.01f * v);
            out[ob + nt * 16] = v;
        }
    }
}

extern "C" void kernel_launch(void* const* d_in, const int* in_sizes, int n_in,
                              void* d_out, int out_size, void* d_ws, size_t ws_size,
                              hipStream_t stream) {
    const float* X   = (const float*)d_in[0];   // (B, N, FIN) fp32
    const int*   adj = (const int*)  d_in[1];   // (B, N, N) int32
    const float* W   = (const float*)d_in[2];   // (FIN, FOUT) fp32
    const float* a   = (const float*)d_in[3];   // (2*FOUT, 1) fp32
    float* out = (float*)d_out;                 // (B, N, FOUT) fp32

    uint16_t* htT = (uint16_t*)d_ws;                       // B*FOUT*N bf16 = 8 MB
    float* s = (float*)(htT + (size_t)B_ * FOUT * N_);     // 65536 floats
    float* t = s + B_ * N_;                                // 65536 floats

    k_h<<<B_ * 4, 256, 0, stream>>>(X, W, a, htT, s, t);
    k_attn<<<B_ * 8, 256, 0, stream>>>(adj, htT, s, t, out);
}

// Round 5
// 238.776 us; speedup vs baseline: 1.0300x; 1.0300x over previous
//
#include <hip/hip_runtime.h>
#include <stdint.h>

#define B_   128
#define N_   512
#define FIN  128
#define FOUT 64

using bf16x8 = __attribute__((ext_vector_type(8))) short;
using f32x4  = __attribute__((ext_vector_type(4))) float;

__device__ inline unsigned short f2bf(float x) {
    union { float f; uint32_t u; } c; c.f = x;
    uint32_t u = c.u;
    return (unsigned short)((u + 0x7FFFu + ((u >> 16) & 1u)) >> 16);  // RNE
}

// ---------------- kernel 1: h = X @ W via bf16 MFMA ----------------
// grid 512 = (b<<2)|quarter, 256 threads. W staged in LDS (16 KB); A-fragments
// loaded directly from global. Writes htT[b][f][j] bf16 + s,t fp32.
__global__ __launch_bounds__(256) void k_h(const float* __restrict__ X,
                                           const float* __restrict__ W,
                                           const float* __restrict__ a,
                                           uint16_t* __restrict__ htT,
                                           float* __restrict__ s,
                                           float* __restrict__ t) {
    __shared__ bf16x8 wl[16 * 64];   // W fragments: 4 ks x 4 nt, 16 KB

    const int b  = blockIdx.x >> 2;
    const int j0 = (blockIdx.x & 3) * 128;
    const int tid = threadIdx.x;
    const int w = tid >> 6, lane = tid & 63;
    const int q = lane >> 4, m = lane & 15;

    // ---- stage W fragments (ks = w): B[k][n], k=q*8+u, n=m ----
#pragma unroll
    for (int nt = 0; nt < 4; ++nt) {
        bf16x8 fr;
#pragma unroll
        for (int u = 0; u < 8; ++u)
            fr[u] = (short)f2bf(W[(w * 32 + q * 8 + u) * FOUT + nt * 16 + m]);
        wl[(w * 4 + nt) * 64 + lane] = fr;
    }
    __syncthreads();

    float asv[4], adv[4];
#pragma unroll
    for (int nt = 0; nt < 4; ++nt) {
        asv[nt] = a[nt * 16 + m];
        adv[nt] = a[FOUT + nt * 16 + m];
    }

    const float* xb = X + ((size_t)(b * N_) + j0) * FIN;

    for (int rl = 0; rl < 2; ++rl) {
        const int rt = w + rl * 4;
        const float* xrow = xb + (size_t)(rt * 16 + m) * FIN + q * 8;
        f32x4 acc[4] = {{0.f,0.f,0.f,0.f},{0.f,0.f,0.f,0.f},
                        {0.f,0.f,0.f,0.f},{0.f,0.f,0.f,0.f}};
#pragma unroll
        for (int ks = 0; ks < 4; ++ks) {
            float4 v0 = *(const float4*)(xrow + ks * 32);
            float4 v1 = *(const float4*)(xrow + ks * 32 + 4);
            bf16x8 af;
            af[0] = (short)f2bf(v0.x); af[1] = (short)f2bf(v0.y);
            af[2] = (short)f2bf(v0.z); af[3] = (short)f2bf(v0.w);
            af[4] = (short)f2bf(v1.x); af[5] = (short)f2bf(v1.y);
            af[6] = (short)f2bf(v1.z); af[7] = (short)f2bf(v1.w);
#pragma unroll
            for (int nt = 0; nt < 4; ++nt)
                acc[nt] = __builtin_amdgcn_mfma_f32_16x16x32_bf16(
                    af, wl[(ks * 4 + nt) * 64 + lane], acc[nt], 0, 0, 0);
        }

        // ---- s,t: per C-row dot with a_src/a_dst, reduce over m lanes ----
        float ps[4], pt[4];
#pragma unroll
        for (int r = 0; r < 4; ++r) {
            float vs = 0.f, vt = 0.f;
#pragma unroll
            for (int nt = 0; nt < 4; ++nt) {
                vs += acc[nt][r] * asv[nt];
                vt += acc[nt][r] * adv[nt];
            }
            vs += __shfl_xor(vs, 1, 64); vs += __shfl_xor(vs, 2, 64);
            vs += __shfl_xor(vs, 4, 64); vs += __shfl_xor(vs, 8, 64);
            vt += __shfl_xor(vt, 1, 64); vt += __shfl_xor(vt, 2, 64);
            vt += __shfl_xor(vt, 4, 64); vt += __shfl_xor(vt, 8, 64);
            ps[r] = vs; pt[r] = vt;
        }
        if (m < 4) {
            float vs = (m == 0) ? ps[0] : (m == 1) ? ps[1] : (m == 2) ? ps[2] : ps[3];
            float vt = (m == 0) ? pt[0] : (m == 1) ? pt[1] : (m == 2) ? pt[2] : pt[3];
            int row = j0 + rt * 16 + q * 4 + m;
            s[b * N_ + row] = vs;
            t[b * N_ + row] = vt;
        }

        // ---- store htT[b][f][j] bf16: C row=q*4+reg -> j, col=m -> f ----
#pragma unroll
        for (int nt = 0; nt < 4; ++nt) {
            uint32_t d0 = (uint32_t)f2bf(acc[nt][0]) | ((uint32_t)f2bf(acc[nt][1]) << 16);
            uint32_t d1 = (uint32_t)f2bf(acc[nt][2]) | ((uint32_t)f2bf(acc[nt][3]) << 16);
            uint2 dd; dd.x = d0; dd.y = d1;
            *(uint2*)(htT + (size_t)(b * FOUT + nt * 16 + m) * N_ + j0 + rt * 16 + q * 4) = dd;
        }
    }
}

// ---------------- kernel 2: attention + aggregation (bf16 MFMA) ----------------
// grid 1024 = (b<<3)|eighth (64 rows/block), 256 threads, one row-tile/wave.
// hstage chunked (32 KB, restaged mid-kernel) -> 34 KB LDS -> 4 blocks/CU.
// adj prefetched DEPTH-4 (8 int4 in flight/wave = 8 KB; x12 waves = 96 KB/CU
// in flight vs ~22 KB latency-BW product) -> adj stream becomes BW-bound.
__global__ __launch_bounds__(256, 4) void k_attn(const int*    __restrict__ adj,
                                                 const uint16_t* __restrict__ htT,
                                                 const float*  __restrict__ s,
                                                 const float*  __restrict__ t,
                                                 float*        __restrict__ out) {
    __shared__ bf16x8 hstage[32 * 64];   // 32 KB, chunk of 8 ks
    __shared__ float  tsh[N_];           // 2 KB

    const int b  = blockIdx.x >> 3;
    const int i0 = (blockIdx.x & 7) * 64;
    const int tid = threadIdx.x;
    const int w = tid >> 6, lane = tid & 63;
    const int q = lane >> 4, m = lane & 15;

    const uint16_t* hb = htT + (size_t)b * FOUT * N_;

    // ---- stage chunk 0 (ks 0..7) + t ----
#pragma unroll
    for (int i = 0; i < 8; ++i) {
        int pi = i * 4 + w, ks = pi >> 2, nt = pi & 3;
        hstage[pi * 64 + lane] =
            *(const bf16x8*)(hb + (size_t)(nt * 16 + m) * N_ + ks * 32 + q * 8);
    }
    *(float2*)&tsh[tid * 2] = *(const float2*)(t + b * N_ + tid * 2);
    __syncthreads();

    const int irow = i0 + w * 16 + m;
    const float s_i = s[b * N_ + irow];
    const int* ar = adj + ((size_t)(b * N_) + irow) * N_;

    f32x4 acc[4] = {{0.f,0.f,0.f,0.f},{0.f,0.f,0.f,0.f},
                    {0.f,0.f,0.f,0.f},{0.f,0.f,0.f,0.f}};
    float lsum = 0.f;

    // ---- depth-4 prefetch queue: ks 0..3 in flight ----
    int4 qa[4], qb[4];
#pragma unroll
    for (int d = 0; d < 4; ++d) {
        qa[d] = *(const int4*)(ar + d * 32 + q * 8);
        qb[d] = *(const int4*)(ar + d * 32 + q * 8 + 4);
    }

    for (int half = 0; half < 2; ++half) {
#pragma unroll
        for (int kk = 0; kk < 8; ++kk) {
            const int ks = half * 8 + kk;
            const int slot = ks & 3;
            int4 c0 = qa[slot];
            int4 c1 = qb[slot];

            // refill slot with ks+4 (clamped; tail re-reads are L2 hits)
            const int kp = (ks + 4 < 16) ? ks + 4 : 15;
            qa[slot] = *(const int4*)(ar + kp * 32 + q * 8);
            qb[slot] = *(const int4*)(ar + kp * 32 + q * 8 + 4);

            const int jb = ks * 32 + q * 8;
            float4 tj0 = *(const float4*)&tsh[jb];
            float4 tj1 = *(const float4*)&tsh[jb + 4];
            float tj[8] = {tj0.x, tj0.y, tj0.z, tj0.w, tj1.x, tj1.y, tj1.z, tj1.w};

            int av[8] = {c0.x, c0.y, c0.z, c0.w, c1.x, c1.y, c1.z, c1.w};
            bf16x8 af;
#pragma unroll
            for (int u = 0; u < 8; ++u) {
                float e = s_i + tj[u];
                e = fmaxf(e, 0.2f * e);               // leaky_relu(e, 0.2)
                float p = (av[u] > 0) ? __expf(e) : 0.0f;
                lsum += p;
                af[u] = (short)f2bf(p);
            }

            bf16x8 bf0 = hstage[(kk * 4 + 0) * 64 + lane];
            bf16x8 bf1 = hstage[(kk * 4 + 1) * 64 + lane];
            bf16x8 bf2 = hstage[(kk * 4 + 2) * 64 + lane];
            bf16x8 bf3 = hstage[(kk * 4 + 3) * 64 + lane];

            acc[0] = __builtin_amdgcn_mfma_f32_16x16x32_bf16(af, bf0, acc[0], 0, 0, 0);
            acc[1] = __builtin_amdgcn_mfma_f32_16x16x32_bf16(af, bf1, acc[1], 0, 0, 0);
            acc[2] = __builtin_amdgcn_mfma_f32_16x16x32_bf16(af, bf2, acc[2], 0, 0, 0);
            acc[3] = __builtin_amdgcn_mfma_f32_16x16x32_bf16(af, bf3, acc[3], 0, 0, 0);
        }
        if (half == 0) {
            __syncthreads();   // all chunk-0 reads done
#pragma unroll
            for (int i = 0; i < 8; ++i) {
                int pi = i * 4 + w, ks = 8 + (pi >> 2), nt = pi & 3;
                hstage[pi * 64 + lane] =
                    *(const bf16x8*)(hb + (size_t)(nt * 16 + m) * N_ + ks * 32 + q * 8);
            }
            __syncthreads();
        }
    }

    // row-sum l over q groups (lanes differ in bits 4,5)
    lsum += __shfl_xor(lsum, 16, 64);
    lsum += __shfl_xor(lsum, 32, 64);

#pragma unroll
    for (int reg = 0; reg < 4; ++reg) {
        float lr = __shfl(lsum, q * 4 + reg, 64);
        float inv = 1.0f / lr;
        int orow = i0 + w * 16 + q * 4 + reg;
        size_t ob = ((size_t)(b * N_) + orow) * FOUT + m;
#pragma unroll
        for (int nt = 0; nt < 4; ++nt) {
            float v = acc[nt][reg] * inv;
            v = fmaxf(v, 0.01f * v);
            out[ob + nt * 16] = v;
        }
    }
}

extern "C" void kernel_launch(void* const* d_in, const int* in_sizes, int n_in,
                              void* d_out, int out_size, void* d_ws, size_t ws_size,
                              hipStream_t stream) {
    const float* X   = (const float*)d_in[0];   // (B, N, FIN) fp32
    const int*   adj = (const int*)  d_in[1];   // (B, N, N) int32
    const float* W   = (const float*)d_in[2];   // (FIN, FOUT) fp32
    const float* a   = (const float*)d_in[3];   // (2*FOUT, 1) fp32
    float* out = (float*)d_out;                 // (B, N, FOUT) fp32

    uint16_t* htT = (uint16_t*)d_ws;                       // B*FOUT*N bf16 = 8 MB
    float* s = (float*)(htT + (size_t)B_ * FOUT * N_);     // 65536 floats
    float* t = s + B_ * N_;                                // 65536 floats

    k_h<<<B_ * 4, 256, 0, stream>>>(X, W, a, htT, s, t);
    k_attn<<<B_ * 8, 256, 0, stream>>>(adj, htT, s, t, out);
}

// Round 6
// 235.156 us; speedup vs baseline: 1.0458x; 1.0154x over previous
//
#include <hip/hip_runtime.h>
#include <stdint.h>

#define B_   128
#define N_   512
#define FIN  128
#define FOUT 64

using bf16x8 = __attribute__((ext_vector_type(8))) short;
using f32x4  = __attribute__((ext_vector_type(4))) float;

__device__ inline unsigned short f2bf(float x) {
    union { float f; uint32_t u; } c; c.f = x;
    uint32_t u = c.u;
    return (unsigned short)((u + 0x7FFFu + ((u >> 16) & 1u)) >> 16);  // RNE
}

// ---------------- kernel 1: h = X @ W via bf16 MFMA ----------------
// grid 512 = (b<<2)|quarter, 256 threads. W staged in LDS (16 KB); A-fragments
// loaded directly from global. Writes htT[b][f][j] bf16 + s,t fp32.
__global__ __launch_bounds__(256) void k_h(const float* __restrict__ X,
                                           const float* __restrict__ W,
                                           const float* __restrict__ a,
                                           uint16_t* __restrict__ htT,
                                           float* __restrict__ s,
                                           float* __restrict__ t) {
    __shared__ bf16x8 wl[16 * 64];   // W fragments: 4 ks x 4 nt, 16 KB

    const int b  = blockIdx.x >> 2;
    const int j0 = (blockIdx.x & 3) * 128;
    const int tid = threadIdx.x;
    const int w = tid >> 6, lane = tid & 63;
    const int q = lane >> 4, m = lane & 15;

    // ---- stage W fragments (ks = w): B[k][n], k=q*8+u, n=m ----
#pragma unroll
    for (int nt = 0; nt < 4; ++nt) {
        bf16x8 fr;
#pragma unroll
        for (int u = 0; u < 8; ++u)
            fr[u] = (short)f2bf(W[(w * 32 + q * 8 + u) * FOUT + nt * 16 + m]);
        wl[(w * 4 + nt) * 64 + lane] = fr;
    }
    __syncthreads();

    float asv[4], adv[4];
#pragma unroll
    for (int nt = 0; nt < 4; ++nt) {
        asv[nt] = a[nt * 16 + m];
        adv[nt] = a[FOUT + nt * 16 + m];
    }

    const float* xb = X + ((size_t)(b * N_) + j0) * FIN;

    for (int rl = 0; rl < 2; ++rl) {
        const int rt = w + rl * 4;
        const float* xrow = xb + (size_t)(rt * 16 + m) * FIN + q * 8;
        f32x4 acc[4] = {{0.f,0.f,0.f,0.f},{0.f,0.f,0.f,0.f},
                        {0.f,0.f,0.f,0.f},{0.f,0.f,0.f,0.f}};
#pragma unroll
        for (int ks = 0; ks < 4; ++ks) {
            float4 v0 = *(const float4*)(xrow + ks * 32);
            float4 v1 = *(const float4*)(xrow + ks * 32 + 4);
            bf16x8 af;
            af[0] = (short)f2bf(v0.x); af[1] = (short)f2bf(v0.y);
            af[2] = (short)f2bf(v0.z); af[3] = (short)f2bf(v0.w);
            af[4] = (short)f2bf(v1.x); af[5] = (short)f2bf(v1.y);
            af[6] = (short)f2bf(v1.z); af[7] = (short)f2bf(v1.w);
#pragma unroll
            for (int nt = 0; nt < 4; ++nt)
                acc[nt] = __builtin_amdgcn_mfma_f32_16x16x32_bf16(
                    af, wl[(ks * 4 + nt) * 64 + lane], acc[nt], 0, 0, 0);
        }

        // ---- s,t: per C-row dot with a_src/a_dst, reduce over m lanes ----
        float ps[4], pt[4];
#pragma unroll
        for (int r = 0; r < 4; ++r) {
            float vs = 0.f, vt = 0.f;
#pragma unroll
            for (int nt = 0; nt < 4; ++nt) {
                vs += acc[nt][r] * asv[nt];
                vt += acc[nt][r] * adv[nt];
            }
            vs += __shfl_xor(vs, 1, 64); vs += __shfl_xor(vs, 2, 64);
            vs += __shfl_xor(vs, 4, 64); vs += __shfl_xor(vs, 8, 64);
            vt += __shfl_xor(vt, 1, 64); vt += __shfl_xor(vt, 2, 64);
            vt += __shfl_xor(vt, 4, 64); vt += __shfl_xor(vt, 8, 64);
            ps[r] = vs; pt[r] = vt;
        }
        if (m < 4) {
            float vs = (m == 0) ? ps[0] : (m == 1) ? ps[1] : (m == 2) ? ps[2] : ps[3];
            float vt = (m == 0) ? pt[0] : (m == 1) ? pt[1] : (m == 2) ? pt[2] : pt[3];
            int row = j0 + rt * 16 + q * 4 + m;
            s[b * N_ + row] = vs;
            t[b * N_ + row] = vt;
        }

        // ---- store htT[b][f][j] bf16: C row=q*4+reg -> j, col=m -> f ----
#pragma unroll
        for (int nt = 0; nt < 4; ++nt) {
            uint32_t d0 = (uint32_t)f2bf(acc[nt][0]) | ((uint32_t)f2bf(acc[nt][1]) << 16);
            uint32_t d1 = (uint32_t)f2bf(acc[nt][2]) | ((uint32_t)f2bf(acc[nt][3]) << 16);
            uint2 dd; dd.x = d0; dd.y = d1;
            *(uint2*)(htT + (size_t)(b * FOUT + nt * 16 + m) * N_ + j0 + rt * 16 + q * 4) = dd;
        }
    }
}

// ---------------- kernel 2: attention + aggregation (bf16 MFMA) ----------------
// grid 512 = (b<<2)|quarter (128 rows), 512 THREADS = 8 waves, one 16-row tile
// per wave. One-shot 64 KB hstage (no mid-kernel restage -> no vmcnt(0) drain
// in the K-loop). LDS 66 KB -> 2 blocks/CU -> 16 waves/CU = 4/SIMD.
// adj prefetched depth-4 (8 int4 in flight/wave).
__global__ __launch_bounds__(512, 4) void k_attn(const int*    __restrict__ adj,
                                                 const uint16_t* __restrict__ htT,
                                                 const float*  __restrict__ s,
                                                 const float*  __restrict__ t,
                                                 float*        __restrict__ out) {
    __shared__ bf16x8 hstage[64 * 64];   // 64 KB, [pi=ks*4+nt][lane]
    __shared__ float  tsh[N_];           // 2 KB

    const int b  = blockIdx.x >> 2;
    const int i0 = (blockIdx.x & 3) * 128;
    const int tid = threadIdx.x;          // 0..511
    const int w = tid >> 6, lane = tid & 63;
    const int q = lane >> 4, m = lane & 15;

    const uint16_t* hb = htT + (size_t)b * FOUT * N_;

    // ---- stage all of H[b] (64 KB) + t, once ----
#pragma unroll
    for (int i = 0; i < 8; ++i) {
        int pi = i * 8 + w, ks = pi >> 2, nt = pi & 3;
        hstage[pi * 64 + lane] =
            *(const bf16x8*)(hb + (size_t)(nt * 16 + m) * N_ + ks * 32 + q * 8);
    }
    tsh[tid] = t[b * N_ + tid];
    __syncthreads();

    const int irow = i0 + w * 16 + m;
    const float s_i = s[b * N_ + irow];
    const int* ar = adj + ((size_t)(b * N_) + irow) * N_;

    f32x4 acc[4] = {{0.f,0.f,0.f,0.f},{0.f,0.f,0.f,0.f},
                    {0.f,0.f,0.f,0.f},{0.f,0.f,0.f,0.f}};
    float lsum = 0.f;

    // ---- depth-4 prefetch queue: ks 0..3 in flight ----
    int4 qa[4], qb[4];
#pragma unroll
    for (int d = 0; d < 4; ++d) {
        qa[d] = *(const int4*)(ar + d * 32 + q * 8);
        qb[d] = *(const int4*)(ar + d * 32 + q * 8 + 4);
    }

#pragma unroll 4
    for (int ks = 0; ks < 16; ++ks) {
        const int slot = ks & 3;
        int4 c0 = qa[slot];
        int4 c1 = qb[slot];

        // refill slot with ks+4 (clamped; tail re-reads are L2 hits)
        const int kp = (ks + 4 < 16) ? ks + 4 : 15;
        qa[slot] = *(const int4*)(ar + kp * 32 + q * 8);
        qb[slot] = *(const int4*)(ar + kp * 32 + q * 8 + 4);

        const int jb = ks * 32 + q * 8;
        float4 tj0 = *(const float4*)&tsh[jb];
        float4 tj1 = *(const float4*)&tsh[jb + 4];
        float tj[8] = {tj0.x, tj0.y, tj0.z, tj0.w, tj1.x, tj1.y, tj1.z, tj1.w};

        int av[8] = {c0.x, c0.y, c0.z, c0.w, c1.x, c1.y, c1.z, c1.w};
        bf16x8 af;
#pragma unroll
        for (int u = 0; u < 8; ++u) {
            float e = s_i + tj[u];
            e = fmaxf(e, 0.2f * e);               // leaky_relu(e, 0.2)
            float p = (av[u] > 0) ? __expf(e) : 0.0f;
            lsum += p;
            af[u] = (short)f2bf(p);
        }

        bf16x8 bf0 = hstage[(ks * 4 + 0) * 64 + lane];
        bf16x8 bf1 = hstage[(ks * 4 + 1) * 64 + lane];
        bf16x8 bf2 = hstage[(ks * 4 + 2) * 64 + lane];
        bf16x8 bf3 = hstage[(ks * 4 + 3) * 64 + lane];

        acc[0] = __builtin_amdgcn_mfma_f32_16x16x32_bf16(af, bf0, acc[0], 0, 0, 0);
        acc[1] = __builtin_amdgcn_mfma_f32_16x16x32_bf16(af, bf1, acc[1], 0, 0, 0);
        acc[2] = __builtin_amdgcn_mfma_f32_16x16x32_bf16(af, bf2, acc[2], 0, 0, 0);
        acc[3] = __builtin_amdgcn_mfma_f32_16x16x32_bf16(af, bf3, acc[3], 0, 0, 0);
    }

    // row-sum l over q groups (lanes differ in bits 4,5)
    lsum += __shfl_xor(lsum, 16, 64);
    lsum += __shfl_xor(lsum, 32, 64);

#pragma unroll
    for (int reg = 0; reg < 4; ++reg) {
        float lr = __shfl(lsum, q * 4 + reg, 64);
        float inv = 1.0f / lr;
        int orow = i0 + w * 16 + q * 4 + reg;
        size_t ob = ((size_t)(b * N_) + orow) * FOUT + m;
#pragma unroll
        for (int nt = 0; nt < 4; ++nt) {
            float v = acc[nt][reg] * inv;
            v = fmaxf(v, 0.01f * v);
            out[ob + nt * 16] = v;
        }
    }
}

extern "C" void kernel_launch(void* const* d_in, const int* in_sizes, int n_in,
                              void* d_out, int out_size, void* d_ws, size_t ws_size,
                              hipStream_t stream) {
    const float* X   = (const float*)d_in[0];   // (B, N, FIN) fp32
    const int*   adj = (const int*)  d_in[1];   // (B, N, N) int32
    const float* W   = (const float*)d_in[2];   // (FIN, FOUT) fp32
    const float* a   = (const float*)d_in[3];   // (2*FOUT, 1) fp32
    float* out = (float*)d_out;                 // (B, N, FOUT) fp32

    uint16_t* htT = (uint16_t*)d_ws;                       // B*FOUT*N bf16 = 8 MB
    float* s = (float*)(htT + (size_t)B_ * FOUT * N_);     // 65536 floats
    float* t = s + B_ * N_;                                // 65536 floats

    k_h<<<B_ * 4, 256, 0, stream>>>(X, W, a, htT, s, t);
    k_attn<<<B_ * 4, 512, 0, stream>>>(adj, htT, s, t, out);
}